// Round 7
// baseline (1570.177 us; speedup 1.0000x reference)
//
#include <hip/hip_runtime.h>
#include <hip/hip_bf16.h>
#include <stdint.h>

#define D_DIM 4096
#define B_DIM 8192

using f32x4  = __attribute__((ext_vector_type(4))) float;
using bf16x8 = __attribute__((ext_vector_type(8))) __bf16;
using uint4v = __attribute__((ext_vector_type(4))) unsigned int;

// round-to-nearest-even f32 -> bf16 bits (finite inputs)
__device__ __forceinline__ unsigned short f2bf(float f) {
  unsigned int u = __builtin_bit_cast(unsigned int, f);
  u = (u + 0x7FFFu + ((u >> 16) & 1u)) >> 16;
  return (unsigned short)u;
}

__device__ __forceinline__ void gload_lds16(const void* g, void* l) {
  __builtin_amdgcn_global_load_lds(
      (const __attribute__((address_space(1))) void*)g,
      (__attribute__((address_space(3))) void*)l, 16, 0, 0);
}

// ---------- prepass: X fp32 -> bf16 ----------
__global__ void cast_x_kernel(const float* __restrict__ x,
                              unsigned short* __restrict__ xb) {
  size_t i = ((size_t)blockIdx.x * blockDim.x + threadIdx.x) * 8;
  const float4* s = reinterpret_cast<const float4*>(x + i);
  float4 a = s[0], b = s[1];
  union { unsigned short u[8]; uint4v v; } o;
  o.u[0] = f2bf(a.x); o.u[1] = f2bf(a.y); o.u[2] = f2bf(a.z); o.u[3] = f2bf(a.w);
  o.u[4] = f2bf(b.x); o.u[5] = f2bf(b.y); o.u[6] = f2bf(b.z); o.u[7] = f2bf(b.w);
  *reinterpret_cast<uint4v*>(xb + i) = o.v;
}

// ---------- prepass: Wt[n][k] = bf16(K[k][n] * M[k][n]) (mask+cast+transpose) ----------
__global__ void wprep_kernel(const float* __restrict__ kw,
                             const int* __restrict__ mk,
                             unsigned short* __restrict__ wt) {
  __shared__ unsigned short tile[64][66];  // [k_local][n_local], padded
  const int tn0 = blockIdx.x * 64;
  const int tk0 = blockIdx.y * 64;
  const int t  = threadIdx.x;     // 256
  const int lr = t >> 4;          // 0..15
  const int lc = (t & 15) * 4;    // 0..60
#pragma unroll
  for (int p = 0; p < 4; ++p) {
    int kk = tk0 + p * 16 + lr;
    const float4 kv = *reinterpret_cast<const float4*>(kw + (size_t)kk * D_DIM + tn0 + lc);
    const int4  mv = *reinterpret_cast<const int4*>(mk + (size_t)kk * D_DIM + tn0 + lc);
    tile[p * 16 + lr][lc + 0] = f2bf(kv.x * (float)mv.x);
    tile[p * 16 + lr][lc + 1] = f2bf(kv.y * (float)mv.y);
    tile[p * 16 + lr][lc + 2] = f2bf(kv.z * (float)mv.z);
    tile[p * 16 + lr][lc + 3] = f2bf(kv.w * (float)mv.w);
  }
  __syncthreads();
#pragma unroll
  for (int p = 0; p < 4; ++p) {
    int nn = tn0 + p * 16 + lr;
    ushort4 o;
    o.x = tile[lc + 0][p * 16 + lr];
    o.y = tile[lc + 1][p * 16 + lr];
    o.z = tile[lc + 2][p * 16 + lr];
    o.w = tile[lc + 3][p * 16 + lr];
    *reinterpret_cast<ushort4*>(wt + (size_t)nn * D_DIM + tk0 + lc) = o;
  }
}

// ---------- m97-structure GEMM: C = A @ Bt^T  (A:[M][K] bf16, Bt:[N][K] bf16) ----------
// EPI 0: C bf16 [M][N].  EPI 1: C fp32 = relu(scaling*acc + bias[col]).
template <int EPI>
__global__ __launch_bounds__(256) void gemm_bt_kernel(
    const unsigned short* __restrict__ A,
    const unsigned short* __restrict__ Bt,
    void* __restrict__ C,
    const float* __restrict__ scaling,
    const float* __restrict__ bias,
    int M, int N, int K) {
  __shared__ unsigned short As[128 * 32];
  __shared__ unsigned short Bs[128 * 32];

  const int nbn = N >> 7;
  int wg = blockIdx.x;
  const int nwg = gridDim.x;        // multiple of 8 here (2048)
  const int cpx = nwg >> 3;
  wg = (wg & 7) * cpx + (wg >> 3);  // XCD-aware bijective swizzle
  const int bm = wg / nbn;
  const int bn = wg % nbn;

  const int t = threadIdx.x;
  const int l = t & 63;
  const int w = t >> 6;
  const int wm = w >> 1, wn = w & 1;

  // staging: 512 16B-chunks per tile; wave w covers bytes [w*1024,(w+1)*1024) per buffer half
  const int ca = w * 64 + l;
  const int ra = ca >> 2;          // tile row 0..63
  const int qa = (ca & 3) * 8;     // k-elem offset within BK=32
  const unsigned short* gA0 = A  + (size_t)(bm * 128 + ra) * K + qa;
  const unsigned short* gA1 = gA0 + (size_t)64 * K;
  const unsigned short* gB0 = Bt + (size_t)(bn * 128 + ra) * K + qa;
  const unsigned short* gB1 = gB0 + (size_t)64 * K;

  unsigned short* lA0 = As + (w * 64) * 8;        // wave-uniform LDS bases
  unsigned short* lA1 = As + (256 + w * 64) * 8;
  unsigned short* lB0 = Bs + (w * 64) * 8;
  unsigned short* lB1 = Bs + (256 + w * 64) * 8;

  const int arow = wm * 64 + (l & 15);
  const int brow = wn * 64 + (l & 15);
  const int koff = (l >> 4) * 8;

  f32x4 acc[4][4] = {};

  for (int kt = 0; kt < (K >> 5); ++kt) {
    gload_lds16(gA0, lA0);
    gload_lds16(gA1, lA1);
    gload_lds16(gB0, lB0);
    gload_lds16(gB1, lB1);
    gA0 += 32; gA1 += 32; gB0 += 32; gB1 += 32;
    __syncthreads();
    bf16x8 af[4], bf[4];
#pragma unroll
    for (int i = 0; i < 4; ++i)
      af[i] = __builtin_bit_cast(bf16x8,
          *reinterpret_cast<const uint4v*>(As + (arow + i * 16) * 32 + koff));
#pragma unroll
    for (int j = 0; j < 4; ++j)
      bf[j] = __builtin_bit_cast(bf16x8,
          *reinterpret_cast<const uint4v*>(Bs + (brow + j * 16) * 32 + koff));
#pragma unroll
    for (int i = 0; i < 4; ++i)
#pragma unroll
      for (int j = 0; j < 4; ++j)
        acc[i][j] = __builtin_amdgcn_mfma_f32_16x16x32_bf16(af[i], bf[j], acc[i][j], 0, 0, 0);
    __syncthreads();
  }

  // epilogue — C/D layout: col = lane&15, row = (lane>>4)*4 + reg  [m89-verified]
  const int crow0 = bm * 128 + wm * 64 + (l >> 4) * 4;
  const int ccol0 = bn * 128 + wn * 64 + (l & 15);
  if (EPI == 0) {
    unsigned short* Cb = (unsigned short*)C;
#pragma unroll
    for (int i = 0; i < 4; ++i)
#pragma unroll
      for (int j = 0; j < 4; ++j) {
        int col = ccol0 + j * 16;
#pragma unroll
        for (int r = 0; r < 4; ++r) {
          int row = crow0 + i * 16 + r;
          Cb[(size_t)row * N + col] = f2bf(acc[i][j][r]);
        }
      }
  } else {
    float* Cf = (float*)C;
    const float s = scaling[0];
#pragma unroll
    for (int i = 0; i < 4; ++i)
#pragma unroll
      for (int j = 0; j < 4; ++j) {
        int col = ccol0 + j * 16;
        float bv = bias[col];
#pragma unroll
        for (int r = 0; r < 4; ++r) {
          int row = crow0 + i * 16 + r;
          float v = s * acc[i][j][r] + bv;
          Cf[(size_t)row * N + col] = v > 0.f ? v : 0.f;
        }
      }
  }
}

extern "C" void kernel_launch(void* const* d_in, const int* in_sizes, int n_in,
                              void* d_out, int out_size, void* d_ws, size_t ws_size,
                              hipStream_t stream) {
  const float* x  = (const float*)d_in[0];
  const float* k0 = (const float*)d_in[1];
  const float* k1 = (const float*)d_in[2];
  const float* k2 = (const float*)d_in[3];
  const int*   m0 = (const int*)d_in[4];
  const int*   m1 = (const int*)d_in[5];
  const int*   m2 = (const int*)d_in[6];
  const float* scaling = (const float*)d_in[7];
  const float* bias    = (const float*)d_in[8];

  // workspace layout (128 MB): [Xb 64MB | Wa 32MB | Wb 32MB]
  //   Y1 (bf16, 64MB) lives in the first half of d_out (fp32 out = 128MB; dead until GEMM3).
  //   W2t reuses Wa after GEMM1; Y2 reuses Xb after GEMM1. All stream-ordered.
  char* ws = (char*)d_ws;
  const size_t XB = (size_t)B_DIM * D_DIM * 2;  // 64 MB
  const size_t WB = (size_t)D_DIM * D_DIM * 2;  // 32 MB
  unsigned short* Xb = (unsigned short*)(ws);
  unsigned short* Wa = (unsigned short*)(ws + XB);
  unsigned short* Wb = (unsigned short*)(ws + XB + WB);
  unsigned short* Y1 = (unsigned short*)d_out;  // first 64MB of the 128MB output buffer
  unsigned short* Y2 = Xb;                      // alias — Xb dead after GEMM1

  cast_x_kernel<<<dim3((unsigned)((size_t)B_DIM * D_DIM / 8 / 256)), dim3(256), 0, stream>>>(x, Xb);
  dim3 wgrid(64, 64);
  wprep_kernel<<<wgrid, dim3(256), 0, stream>>>(k0, m0, Wa);
  wprep_kernel<<<wgrid, dim3(256), 0, stream>>>(k1, m1, Wb);

  const int grid = (B_DIM / 128) * (D_DIM / 128);  // 2048

  gemm_bt_kernel<0><<<dim3(grid), dim3(256), 0, stream>>>(
      Xb, Wa, (void*)Y1, nullptr, nullptr, B_DIM, D_DIM, D_DIM);

  // W2 prep after GEMM1 so it can overwrite Wa's slot (stream-ordered)
  wprep_kernel<<<wgrid, dim3(256), 0, stream>>>(k2, m2, Wa);

  gemm_bt_kernel<0><<<dim3(grid), dim3(256), 0, stream>>>(
      Y1, Wb, (void*)Y2, nullptr, nullptr, B_DIM, D_DIM, D_DIM);

  gemm_bt_kernel<1><<<dim3(grid), dim3(256), 0, stream>>>(
      Y2, Wa, d_out, scaling, bias, B_DIM, D_DIM, D_DIM);
}

// Round 8
// 1168.300 us; speedup vs baseline: 1.3440x; 1.3440x over previous
//
#include <hip/hip_runtime.h>
#include <hip/hip_bf16.h>
#include <stdint.h>

#define D_DIM 4096
#define B_DIM 8192
#define NTILE 64  // K / 64

using f32x4  = __attribute__((ext_vector_type(4))) float;
using bf16x8 = __attribute__((ext_vector_type(8))) __bf16;
using uint4v = __attribute__((ext_vector_type(4))) unsigned int;

#define BAR() asm volatile("s_barrier" ::: "memory")
#define WAITV(n) asm volatile("s_waitcnt vmcnt(" #n ")" ::: "memory")

// round-to-nearest-even f32 -> bf16 bits (finite inputs)
__device__ __forceinline__ unsigned short f2bf(float f) {
  unsigned int u = __builtin_bit_cast(unsigned int, f);
  u = (u + 0x7FFFu + ((u >> 16) & 1u)) >> 16;
  return (unsigned short)u;
}

__device__ __forceinline__ void gload_lds16(const void* g, void* l) {
  __builtin_amdgcn_global_load_lds(
      (const __attribute__((address_space(1))) void*)g,
      (__attribute__((address_space(3))) void*)l, 16, 0, 0);
}

// ---------- prepass: X fp32 -> bf16 ----------
__global__ void cast_x_kernel(const float* __restrict__ x,
                              unsigned short* __restrict__ xb) {
  size_t i = ((size_t)blockIdx.x * blockDim.x + threadIdx.x) * 8;
  const float4* s = reinterpret_cast<const float4*>(x + i);
  float4 a = s[0], b = s[1];
  union { unsigned short u[8]; uint4v v; } o;
  o.u[0] = f2bf(a.x); o.u[1] = f2bf(a.y); o.u[2] = f2bf(a.z); o.u[3] = f2bf(a.w);
  o.u[4] = f2bf(b.x); o.u[5] = f2bf(b.y); o.u[6] = f2bf(b.z); o.u[7] = f2bf(b.w);
  *reinterpret_cast<uint4v*>(xb + i) = o.v;
}

// ---------- prepass: Wt[n][k] = bf16(K[k][n] * M[k][n]) (mask+cast+transpose) ----------
__global__ void wprep_kernel(const float* __restrict__ kw,
                             const int* __restrict__ mk,
                             unsigned short* __restrict__ wt) {
  __shared__ unsigned short tile[64][66];
  const int tn0 = blockIdx.x * 64;
  const int tk0 = blockIdx.y * 64;
  const int t  = threadIdx.x;
  const int lr = t >> 4;
  const int lc = (t & 15) * 4;
#pragma unroll
  for (int p = 0; p < 4; ++p) {
    int kk = tk0 + p * 16 + lr;
    const float4 kv = *reinterpret_cast<const float4*>(kw + (size_t)kk * D_DIM + tn0 + lc);
    const int4  mv = *reinterpret_cast<const int4*>(mk + (size_t)kk * D_DIM + tn0 + lc);
    tile[p * 16 + lr][lc + 0] = f2bf(kv.x * (float)mv.x);
    tile[p * 16 + lr][lc + 1] = f2bf(kv.y * (float)mv.y);
    tile[p * 16 + lr][lc + 2] = f2bf(kv.z * (float)mv.z);
    tile[p * 16 + lr][lc + 3] = f2bf(kv.w * (float)mv.w);
  }
  __syncthreads();
#pragma unroll
  for (int p = 0; p < 4; ++p) {
    int nn = tn0 + p * 16 + lr;
    ushort4 o;
    o.x = tile[lc + 0][p * 16 + lr];
    o.y = tile[lc + 1][p * 16 + lr];
    o.z = tile[lc + 2][p * 16 + lr];
    o.w = tile[lc + 3][p * 16 + lr];
    *reinterpret_cast<ushort4*>(wt + (size_t)nn * D_DIM + tk0 + lc) = o;
  }
}

// ---------- 256x256 8-wave 8-phase GEMM: C = A @ Bt^T ----------
// A:[M][K] bf16, Bt:[N][K] bf16. EPI 0: C bf16. EPI 1: C fp32 relu(s*acc+bias).
//
// LDS: 2 buffers x 4 half-tiles {0:A-klo, 1:A-khi, 2:B-klo, 3:B-khi},
// each half = 256 rows x 32 k bf16 (16 KB, 64-B rows), swizzle chunk^=row&3.
// Per tile: 4 phases (kstep x Mhalf); counted vmcnt(6) at tile boundary only.
template <int EPI>
__global__ __launch_bounds__(512, 2) void gemm256_kernel(
    const unsigned short* __restrict__ A,
    const unsigned short* __restrict__ Bt,
    void* __restrict__ C,
    const float* __restrict__ scaling,
    const float* __restrict__ bias,
    int M, int N, int K) {
  __shared__ unsigned short lds[2][4][8192];  // 128 KiB

  const int nbn = N >> 8;
  int wg = blockIdx.x;
  const int nwg = gridDim.x;       // multiple of 8 (512)
  const int cpx = nwg >> 3;
  wg = (wg & 7) * cpx + (wg >> 3); // XCD-aware bijective swizzle
  const int bm = wg / nbn;
  const int bn = wg % nbn;

  const int tid = threadIdx.x;
  const int l = tid & 63;
  const int w = tid >> 6;   // wave 0..7
  const int wm = w >> 2;    // 0..1  (M half of block)
  const int wn = w & 3;     // 0..3  (N quarter of block)

  // staging source (per thread): LDS slot (row=tid>>2, chunk=tid&3) holds
  // global chunk (tid&3)^(row&3)  [inverse swizzle on source, rule 21]
  const int srow = tid >> 2;                    // 0..127 (issue1: +128)
  const int schunk = (tid & 3) ^ (srow & 3);
  const unsigned short* gA = A  + (size_t)(bm * 256 + srow) * K + schunk * 8;
  const unsigned short* gB = Bt + (size_t)(bn * 256 + srow) * K + schunk * 8;

  // frag-read swizzle: row%4 == l%4 for all frags -> lane-only chunk xor
  const int lrow = l & 15;
  const int kch  = ((l >> 4) ^ (l & 3)) * 8;    // elem offset of 16-B chunk

  f32x4 acc[8][4] = {};
  bf16x8 pA[4], pB[4];

#define STAGE(gbase, tt, kh, bb, h) do {                                   \
    const unsigned short* _s = (gbase) + (size_t)(tt) * 64 + (kh) * 32;    \
    gload_lds16(_s, &lds[bb][h][w * 512]);                                 \
    gload_lds16(_s + (size_t)128 * K, &lds[bb][h][4096 + w * 512]);        \
  } while (0)

#define LDA(b_, ks_, mh_) do {                                             \
    _Pragma("unroll")                                                      \
    for (int i = 0; i < 4; ++i) {                                          \
      int row = wm * 128 + ((mh_) * 4 + i) * 16 + lrow;                    \
      pA[i] = __builtin_bit_cast(bf16x8,                                   \
          *reinterpret_cast<const uint4v*>(&lds[b_][ks_][row * 32 + kch]));\
    } } while (0)

#define LDB(b_, ks_) do {                                                  \
    _Pragma("unroll")                                                      \
    for (int j = 0; j < 4; ++j) {                                          \
      int row = wn * 64 + j * 16 + lrow;                                   \
      pB[j] = __builtin_bit_cast(bf16x8,                                   \
          *reinterpret_cast<const uint4v*>(&lds[b_][2 + (ks_)][row * 32 + kch])); \
    } } while (0)

#define MFMA16(mh_) do {                                                   \
    _Pragma("unroll")                                                      \
    for (int i = 0; i < 4; ++i)                                            \
      _Pragma("unroll")                                                    \
      for (int j = 0; j < 4; ++j)                                          \
        acc[(mh_) * 4 + i][j] = __builtin_amdgcn_mfma_f32_16x16x32_bf16(   \
            pA[i], pB[j], acc[(mh_) * 4 + i][j], 0, 0, 0);                 \
  } while (0)

  // prologue: tile0 all 4 halves, then tile1's first 3 (14 loads);
  // vmcnt(6) -> tile0 fully landed, 3 halves in flight.
  STAGE(gB, 0, 0, 0, 2);
  STAGE(gA, 0, 0, 0, 0);
  STAGE(gB, 0, 1, 0, 3);
  STAGE(gA, 0, 1, 0, 1);
  STAGE(gB, 1, 0, 1, 2);
  STAGE(gA, 1, 0, 1, 0);
  STAGE(gB, 1, 1, 1, 3);
  WAITV(6);
  BAR();

  for (int t = 0; t < NTILE; ++t) {
    const int b = t & 1;
    // phase 0: ks=0, mh=0; stage A-khi^{t+1} (slot freed end of tile t-1)
    LDB(b, 0);
    LDA(b, 0, 0);
    if (t + 1 < NTILE) STAGE(gA, t + 1, 1, b ^ 1, 1);
    BAR();
    __builtin_amdgcn_s_setprio(1);
    MFMA16(0);
    __builtin_amdgcn_s_setprio(0);
    BAR();
    // phase 1: ks=0, mh=1 (pB reused); stage B-klo^{t+2} (B-klo^t consumed ph0)
    LDA(b, 0, 1);
    if (t + 2 < NTILE) STAGE(gB, t + 2, 0, b, 2);
    BAR();
    __builtin_amdgcn_s_setprio(1);
    MFMA16(1);
    __builtin_amdgcn_s_setprio(0);
    BAR();
    // phase 2: ks=1, mh=0; stage A-klo^{t+2} (A-klo^t consumed ph0,1)
    LDB(b, 1);
    LDA(b, 1, 0);
    if (t + 2 < NTILE) STAGE(gA, t + 2, 0, b, 0);
    BAR();
    __builtin_amdgcn_s_setprio(1);
    MFMA16(0);
    __builtin_amdgcn_s_setprio(0);
    BAR();
    // phase 3: ks=1, mh=1; stage B-khi^{t+2} (B-khi^t consumed ph2)
    LDA(b, 1, 1);
    if (t + 2 < NTILE) STAGE(gB, t + 2, 1, b, 3);
    BAR();
    __builtin_amdgcn_s_setprio(1);
    MFMA16(1);
    __builtin_amdgcn_s_setprio(0);
    // tile boundary: counted wait (never 0 mid-loop; 0 entering last tile)
    if (t + 1 < NTILE) {
      if (t + 1 == NTILE - 1) { WAITV(0); } else { WAITV(6); }
      BAR();
    }
  }

#undef STAGE
#undef LDA
#undef LDB
#undef MFMA16

  // epilogue — C/D layout: col = lane&15, row = (lane>>4)*4 + reg  [m89-verified]
  const int crow0 = bm * 256 + wm * 128 + (l >> 4) * 4;
  const int ccol0 = bn * 256 + wn * 64 + (l & 15);
  if (EPI == 0) {
    unsigned short* Cb = (unsigned short*)C;
#pragma unroll
    for (int mi = 0; mi < 8; ++mi)
#pragma unroll
      for (int j = 0; j < 4; ++j) {
        int col = ccol0 + j * 16;
#pragma unroll
        for (int r = 0; r < 4; ++r) {
          int row = crow0 + mi * 16 + r;
          Cb[(size_t)row * N + col] = f2bf(acc[mi][j][r]);
        }
      }
  } else {
    float* Cf = (float*)C;
    const float s = scaling[0];
#pragma unroll
    for (int mi = 0; mi < 8; ++mi)
#pragma unroll
      for (int j = 0; j < 4; ++j) {
        int col = ccol0 + j * 16;
        float bv = bias[col];
#pragma unroll
        for (int r = 0; r < 4; ++r) {
          int row = crow0 + mi * 16 + r;
          float v = s * acc[mi][j][r] + bv;
          Cf[(size_t)row * N + col] = v > 0.f ? v : 0.f;
        }
      }
  }
}

extern "C" void kernel_launch(void* const* d_in, const int* in_sizes, int n_in,
                              void* d_out, int out_size, void* d_ws, size_t ws_size,
                              hipStream_t stream) {
  const float* x  = (const float*)d_in[0];
  const float* k0 = (const float*)d_in[1];
  const float* k1 = (const float*)d_in[2];
  const float* k2 = (const float*)d_in[3];
  const int*   m0 = (const int*)d_in[4];
  const int*   m1 = (const int*)d_in[5];
  const int*   m2 = (const int*)d_in[6];
  const float* scaling = (const float*)d_in[7];
  const float* bias    = (const float*)d_in[8];

  // workspace (128 MB): [Xb 64MB | Wa 32MB | Wb 32MB]
  // Y1 (bf16, 64MB) in first half of d_out (dead until GEMM3 overwrites).
  // W2t reuses Wa after GEMM1; Y2 reuses Xb after GEMM1. Stream-ordered.
  char* ws = (char*)d_ws;
  const size_t XB = (size_t)B_DIM * D_DIM * 2;
  const size_t WB = (size_t)D_DIM * D_DIM * 2;
  unsigned short* Xb = (unsigned short*)(ws);
  unsigned short* Wa = (unsigned short*)(ws + XB);
  unsigned short* Wb = (unsigned short*)(ws + XB + WB);
  unsigned short* Y1 = (unsigned short*)d_out;
  unsigned short* Y2 = Xb;

  cast_x_kernel<<<dim3((unsigned)((size_t)B_DIM * D_DIM / 8 / 256)), dim3(256), 0, stream>>>(x, Xb);
  dim3 wgrid(64, 64);
  wprep_kernel<<<wgrid, dim3(256), 0, stream>>>(k0, m0, Wa);
  wprep_kernel<<<wgrid, dim3(256), 0, stream>>>(k1, m1, Wb);

  const int grid = (B_DIM / 256) * (D_DIM / 256);  // 512

  gemm256_kernel<0><<<dim3(grid), dim3(512), 0, stream>>>(
      Xb, Wa, (void*)Y1, nullptr, nullptr, B_DIM, D_DIM, D_DIM);

  wprep_kernel<<<wgrid, dim3(256), 0, stream>>>(k2, m2, Wa);

  gemm256_kernel<0><<<dim3(grid), dim3(512), 0, stream>>>(
      Y1, Wb, (void*)Y2, nullptr, nullptr, B_DIM, D_DIM, D_DIM);

  gemm256_kernel<1><<<dim3(grid), dim3(512), 0, stream>>>(
      Y2, Wa, d_out, scaling, bias, B_DIM, D_DIM, D_DIM);
}